// Round 2
// baseline (146.616 us; speedup 1.0000x reference)
//
#include <hip/hip_runtime.h>

// Problem constants (match reference)
#define T_TICKS 128
#define NCH     1536
#define NCPAIR  10000
#define NCROSS  30000
#define E_EDGES 120000
#define TG      4               // ticks per thread
#define NTG     (T_TICKS / TG)  // 32 tick groups
#define CAP     32              // bucket capacity (deg ~ Poisson(4), max ~20)
#define BN      256             // nodes per k_gat block
#define NBLK    ((NCROSS + BN - 1) / BN)   // 118
#define NXPOS   (NTG * NCH)                // 49152 float4 transpose items
#define PREP_ITEMS (NCROSS + E_EDGES + NXPOS)

// ---------------- prep: per-node tick-static scalars + edge scatter + x transpose
// Key identity: h(t)·a = hB + x[chA][t]*hA1 + x[chB][t]*hB1 + t*hT, where
// hA1/hB1/hT are GLOBAL scalars. Per node: {sB,pB,chA,chB} (16B) + dB (4B).
// Bucket is NODE-major [n][CAP] (128-B rows): k_gat reads 4 slots in ONE int4
// load -> all 4 c4 gathers issue in parallel (kills the serial
// bucket->gather latency chain that made round-1 k_gat latency-bound).

__global__ void k_prep(const float* __restrict__ x,
                       const int* __restrict__ c0, const int* __restrict__ c1,
                       const int* __restrict__ c2,
                       const int* __restrict__ g01, const int* __restrict__ g12,
                       const int* __restrict__ g20,
                       const float* __restrict__ r01,
                       const float* __restrict__ r12,
                       const float* __restrict__ r20,
                       const float* __restrict__ Wg,
                       const float* __restrict__ bg,
                       const float* __restrict__ as_,
                       const float* __restrict__ ad_,
                       const float* __restrict__ Wm,
                       const int* __restrict__ e_src,
                       const int* __restrict__ e_dst,
                       int* __restrict__ counts,
                       int* __restrict__ bucket,
                       float4* __restrict__ c4,
                       float* __restrict__ dBv,
                       float4* __restrict__ xT4) {
    const int gid = blockIdx.x * 256 + threadIdx.x;
    if (gid < NCROSS) {
        const int n = gid;
        int iA, iB, m;
        float pA, pB;
        const int* cA;
        const int* cB;
        const float* ray;
        if (n < NCPAIR) {
            m = n; cA = c0; cB = c1; pA = 0.f; pB = 1.f; ray = r01;
            iA = g01[2 * m]; iB = g01[2 * m + 1];
        } else if (n < 2 * NCPAIR) {
            m = n - NCPAIR; cA = c1; cB = c2; pA = 1.f; pB = 2.f; ray = r12;
            iA = g12[2 * m]; iB = g12[2 * m + 1];
        } else {
            m = n - 2 * NCPAIR; cA = c2; cB = c0; pA = 2.f; pB = 0.f; ray = r20;
            iA = g20[2 * m]; iB = g20[2 * m + 1];
        }
        const int chA = cA[iA];
        const int chB = cB[iB];
        const float rx = ray[2 * m];
        const float ry = ray[2 * m + 1];

        float base[4];
#pragma unroll
        for (int c = 0; c < 4; c++) {
            base[c] = bg[c]
                    + (float)iA  * Wg[1 * 4 + c] + (float)chA * Wg[2 * 4 + c]
                    + pA         * Wg[4 * 4 + c]
                    + (float)iB  * Wg[6 * 4 + c] + (float)chB * Wg[7 * 4 + c]
                    + pB         * Wg[9 * 4 + c]
                    + rx         * Wg[10 * 4 + c] + ry * Wg[11 * 4 + c];
        }
        float sB = 0.f, dB = 0.f, pBs = 0.f;
#pragma unroll
        for (int c = 0; c < 4; c++) {
            sB  = fmaf(base[c], as_[c], sB);
            dB  = fmaf(base[c], ad_[c], dB);
            pBs = fmaf(base[c], Wm[c], pBs);
        }
        c4[n]  = make_float4(sB, pBs, __int_as_float(chA), __int_as_float(chB));
        dBv[n] = dB;
    } else if (gid < NCROSS + E_EDGES) {
        const int i = gid - NCROSS;
        const int s = e_src[i];
        const int d = e_dst[i];
        const int slot = atomicAdd(&counts[d], 1);
        if (slot < CAP) bucket[(size_t)d * CAP + slot] = s;
    } else if (gid < PREP_ITEMS) {
        // transpose x[c][t] -> xT[tg][c][4]: per-tick-group slice is 24 KB
        // contiguous so k_gat stages it coalesced.
        const int i = gid - (NCROSS + E_EDGES);
        const int tg = i / NCH;
        const int c = i - tg * NCH;
        xT4[i] = *(const float4*)(x + c * T_TICKS + tg * TG);
    }
}

// ---------------- GAT aggregation + MLP + sigmoid (recompute-from-x version)

__device__ __forceinline__ void upd(float& mx, float& den, float& p,
                                    const float e, const float pj) {
    const float dif = e - mx;
    const float ex = __expf(-fabsf(dif));
    const bool g = dif > 0.f;
    const float scale = g ? ex : 1.f;
    const float w = g ? 1.f : ex;
    mx = g ? e : mx;
    den = fmaf(den, scale, w);
    p = fmaf(p, scale, w * pj);
}

__device__ __forceinline__ void edge_proc(const float4 cs, const float4* xs,
                                          const float sA1, const float sB1,
                                          const float pA1, const float pB1,
                                          const float* ts, const float* tp,
                                          const float* dd,
                                          float* mx, float* den, float* pa) {
    const float4 a4 = xs[__float_as_int(cs.z)];
    const float4 b4 = xs[__float_as_int(cs.w)];
    const float a[4] = {a4.x, a4.y, a4.z, a4.w};
    const float b[4] = {b4.x, b4.y, b4.z, b4.w};
#pragma unroll
    for (int k = 0; k < TG; k++) {
        const float sv = cs.x + a[k] * sA1 + b[k] * sB1 + ts[k];
        const float pv = cs.y + a[k] * pA1 + b[k] * pB1 + tp[k];
        float e = sv + dd[k];
        e = fmaxf(e, 0.2f * e);
        upd(mx[k], den[k], pa[k], e, pv);
    }
}

__global__ __launch_bounds__(BN, 5) void k_gat(
        const float4* __restrict__ xT4,
        const float4* __restrict__ c4,
        const float* __restrict__ dBv,
        const int* __restrict__ counts,
        const int* __restrict__ bucket,
        const float* __restrict__ Wg,
        const float* __restrict__ as_,
        const float* __restrict__ ad_,
        const float* __restrict__ Wm,
        const float* __restrict__ bm,
        float* __restrict__ out) {
    // XCD-confined swizzle: 8 consecutive blocks = same node window on 8 XCDs,
    // one tg each; each XCD's L2 holds c4 (0.48MB) + its x slices + hot bucket
    // half-lines (1.92MB).
    const int lid = blockIdx.x;
    const int xcd = lid & 7;
    const int s   = lid >> 3;          // 0 .. 4*NBLK-1
    const int q   = s / NBLK;          // 0..3
    const int nb  = s - q * NBLK;
    const int tg  = xcd + 8 * q;
    const int bbase = nb * BN;
    const int tid = threadIdx.x;
    const int wsz = min(BN, NCROSS - bbase);

    __shared__ float4 xs[NCH];         // 24 KB: x[:, tg*4 .. tg*4+3]
    __shared__ int perm[BN];           // packed: local idx | deg<<16
    __shared__ int bins[CAP + 1];
    __shared__ int boff[CAP + 1];
    __shared__ float lres[TG][BN];

    // stage x tick-group slice (coalesced from transposed layout)
    for (int c = tid; c < NCH; c += BN) xs[c] = xT4[tg * NCH + c];

    // 9 global projection scalars (uniform -> scalar loads)
    float sA1 = 0, dA1 = 0, pA1 = 0, sB1 = 0, dB1 = 0, pB1 = 0,
          sT = 0, dT = 0, pT = 0;
#pragma unroll
    for (int c = 0; c < 4; c++) {
        const float va = as_[c], vd = ad_[c], vm = Wm[c];
        const float w0 = Wg[c], w5 = Wg[5 * 4 + c], w12 = Wg[12 * 4 + c];
        sA1 = fmaf(w0, va, sA1);  dA1 = fmaf(w0, vd, dA1);  pA1 = fmaf(w0, vm, pA1);
        sB1 = fmaf(w5, va, sB1);  dB1 = fmaf(w5, vd, dB1);  pB1 = fmaf(w5, vm, pB1);
        sT  = fmaf(w12, va, sT);  dT  = fmaf(w12, vd, dT);  pT  = fmaf(w12, vm, pT);
    }

    // ---- block-local descending-degree counting sort (wave-uniform trips) ----
    int deg0 = 0;
    if (tid < wsz) deg0 = min(counts[bbase + tid], CAP);
    if (tid <= CAP) bins[tid] = 0;
    __syncthreads();
    int lp = 0;
    if (tid < wsz) lp = atomicAdd(&bins[deg0], 1);
    __syncthreads();
    if (tid == 0) {
        int run = 0;
        for (int d = CAP; d >= 0; d--) { boff[d] = run; run += bins[d]; }
    }
    __syncthreads();
    if (tid < wsz) perm[boff[deg0] + lp] = tid | (deg0 << 16);
    __syncthreads();

    if (tid < wsz) {
        const int pk = perm[tid];
        const int nloc = pk & 0xffff;
        const int deg = pk >> 16;          // no dependent counts[] re-read
        const int n = bbase + nloc;

        const float4 cc = c4[n];
        const float4 a4 = xs[__float_as_int(cc.z)];
        const float4 b4 = xs[__float_as_int(cc.w)];
        const float dB = dBv[n];
        const float a[4] = {a4.x, a4.y, a4.z, a4.w};
        const float b[4] = {b4.x, b4.y, b4.z, b4.w};

        float dd[TG], ts[TG], tp[TG];
#pragma unroll
        for (int k = 0; k < TG; k++) {
            const float tk = (float)(tg * TG + k);
            dd[k] = dB + a[k] * dA1 + b[k] * dB1 + tk * dT;
            ts[k] = tk * sT;
            tp[k] = tk * pT;
        }
        float mx[TG], den[TG], pa[TG];
#pragma unroll
        for (int k = 0; k < TG; k++) { mx[k] = -INFINITY; den[k] = 0.f; pa[k] = 0.f; }

        // node-major bucket row: one int4 = 4 slots -> 4-deep gather ILP.
        // deg is wave-uniform after the sort, so the m-guards don't diverge.
        const int* bkt = bucket + (size_t)n * CAP;
        for (int j = 0; j < deg; j += 4) {
            const int4 bb = *(const int4*)(bkt + j);
            const int m = deg - j;
            float4 cs0 = c4[bb.x];
            float4 cs1 = make_float4(0.f, 0.f, 0.f, 0.f);
            float4 cs2 = cs1, cs3 = cs1;
            if (m > 1) cs1 = c4[bb.y];
            if (m > 2) cs2 = c4[bb.z];
            if (m > 3) cs3 = c4[bb.w];
            edge_proc(cs0, xs, sA1, sB1, pA1, pB1, ts, tp, dd, mx, den, pa);
            if (m > 1) edge_proc(cs1, xs, sA1, sB1, pA1, pB1, ts, tp, dd, mx, den, pa);
            if (m > 2) edge_proc(cs2, xs, sA1, sB1, pA1, pB1, ts, tp, dd, mx, den, pa);
            if (m > 3) edge_proc(cs3, xs, sA1, sB1, pA1, pB1, ts, tp, dd, mx, den, pa);
        }

        const float bb2 = bm[0];
#pragma unroll
        for (int k = 0; k < TG; k++) {
            const float logit = pa[k] / (den[k] + 1e-9f) + bb2;
            lres[k][nloc] = 1.f / (1.f + __expf(-logit));
        }
    }
    __syncthreads();
    if (tid < wsz) {
#pragma unroll
        for (int k = 0; k < TG; k++) {
            out[(size_t)(tg * TG + k) * NCROSS + bbase + tid] = lres[k][tid];
        }
    }
}

// ---------------- launch ----------------

extern "C" void kernel_launch(void* const* d_in, const int* in_sizes, int n_in,
                              void* d_out, int out_size, void* d_ws, size_t ws_size,
                              hipStream_t stream) {
    const float* x   = (const float*)d_in[0];
    const int* c0  = (const int*)d_in[1];
    const int* c1  = (const int*)d_in[2];
    const int* c2  = (const int*)d_in[3];
    const int* g01 = (const int*)d_in[4];
    const int* g12 = (const int*)d_in[5];
    const int* g20 = (const int*)d_in[6];
    const float* r01 = (const float*)d_in[7];
    const float* r12 = (const float*)d_in[8];
    const float* r20 = (const float*)d_in[9];
    const int* edges = (const int*)d_in[10];          // [2, E]
    const float* Wg  = (const float*)d_in[11];
    const float* as_ = (const float*)d_in[12];
    const float* ad_ = (const float*)d_in[13];
    const float* bg  = (const float*)d_in[14];
    const float* Wm  = (const float*)d_in[15];
    const float* bm  = (const float*)d_in[16];
    float* out = (float*)d_out;

    const int* e_src = edges;
    const int* e_dst = edges + E_EDGES;

    // workspace layout (~5.3 MB total)
    char* ws = (char*)d_ws;
    size_t off = 0;
    int* counts = (int*)(ws + off); off += NCROSS * sizeof(int);
    off = (off + 255) & ~(size_t)255;
    int* bucket = (int*)(ws + off); off += (size_t)NCROSS * CAP * sizeof(int);  // 3.84 MB
    off = (off + 255) & ~(size_t)255;
    float4* c4 = (float4*)(ws + off); off += (size_t)NCROSS * sizeof(float4);   // 480 KB
    off = (off + 255) & ~(size_t)255;
    float* dBv = (float*)(ws + off); off += NCROSS * sizeof(float);             // 120 KB
    off = (off + 255) & ~(size_t)255;
    float4* xT4 = (float4*)(ws + off); off += (size_t)NXPOS * sizeof(float4);   // 768 KB
    (void)ws_size; (void)n_in; (void)in_sizes; (void)out_size;

    hipMemsetAsync(counts, 0, NCROSS * sizeof(int), stream);

    k_prep<<<(PREP_ITEMS + 255) / 256, 256, 0, stream>>>(
        x, c0, c1, c2, g01, g12, g20, r01, r12, r20, Wg, bg, as_, ad_, Wm,
        e_src, e_dst, counts, bucket, c4, dBv, xT4);

    k_gat<<<NBLK * NTG, BN, 0, stream>>>(xT4, c4, dBv, counts, bucket,
                                         Wg, as_, ad_, Wm, bm, out);
}

// Round 3
// 130.373 us; speedup vs baseline: 1.1246x; 1.1246x over previous
//
#include <hip/hip_runtime.h>

// Problem constants (match reference)
#define T_TICKS 128
#define NCH     1536
#define NCPAIR  10000
#define NCROSS  30000
#define E_EDGES 120000
#define TG      4               // ticks per thread
#define TGB     16              // ticks per block (4 tick-lanes x TG)
#define NCHUNK  (T_TICKS / TGB) // 8 tick chunks
#define CAP     32              // bucket capacity (deg ~ Poisson(4))
#define BNODE   64              // nodes per k_gat block
#define NBLKN   ((NCROSS + BNODE - 1) / BNODE)  // 469
#define PREP_ITEMS (NCROSS + E_EDGES)

// ---------------- prep: per-node tick-static scalars + edge scatter ----------
// h(t)·a = hB + x[chA][t]*hA1 + x[chB][t]*hB1 + t*hT with hA1/hB1/hT global
// scalars. Per node: c4 = {sB, pB, dB, chA|chB<<16} -- ONE 16-B record serves
// both "own" and "neighbor" roles. Bucket node-major [n][CAP] (128-B rows).

__global__ void k_prep(const float* __restrict__ x,
                       const int* __restrict__ c0, const int* __restrict__ c1,
                       const int* __restrict__ c2,
                       const int* __restrict__ g01, const int* __restrict__ g12,
                       const int* __restrict__ g20,
                       const float* __restrict__ r01,
                       const float* __restrict__ r12,
                       const float* __restrict__ r20,
                       const float* __restrict__ Wg,
                       const float* __restrict__ bg,
                       const float* __restrict__ as_,
                       const float* __restrict__ ad_,
                       const float* __restrict__ Wm,
                       const int* __restrict__ e_src,
                       const int* __restrict__ e_dst,
                       int* __restrict__ counts,
                       int* __restrict__ bucket,
                       float4* __restrict__ c4) {
    const int gid = blockIdx.x * 256 + threadIdx.x;
    if (gid < NCROSS) {
        const int n = gid;
        int iA, iB, m;
        float pA, pB;
        const int* cA;
        const int* cB;
        const float* ray;
        if (n < NCPAIR) {
            m = n; cA = c0; cB = c1; pA = 0.f; pB = 1.f; ray = r01;
            iA = g01[2 * m]; iB = g01[2 * m + 1];
        } else if (n < 2 * NCPAIR) {
            m = n - NCPAIR; cA = c1; cB = c2; pA = 1.f; pB = 2.f; ray = r12;
            iA = g12[2 * m]; iB = g12[2 * m + 1];
        } else {
            m = n - 2 * NCPAIR; cA = c2; cB = c0; pA = 2.f; pB = 0.f; ray = r20;
            iA = g20[2 * m]; iB = g20[2 * m + 1];
        }
        const int chA = cA[iA];
        const int chB = cB[iB];
        const float rx = ray[2 * m];
        const float ry = ray[2 * m + 1];

        float base[4];
#pragma unroll
        for (int c = 0; c < 4; c++) {
            base[c] = bg[c]
                    + (float)iA  * Wg[1 * 4 + c] + (float)chA * Wg[2 * 4 + c]
                    + pA         * Wg[4 * 4 + c]
                    + (float)iB  * Wg[6 * 4 + c] + (float)chB * Wg[7 * 4 + c]
                    + pB         * Wg[9 * 4 + c]
                    + rx         * Wg[10 * 4 + c] + ry * Wg[11 * 4 + c];
        }
        float sB = 0.f, dB = 0.f, pBs = 0.f;
#pragma unroll
        for (int c = 0; c < 4; c++) {
            sB  = fmaf(base[c], as_[c], sB);
            dB  = fmaf(base[c], ad_[c], dB);
            pBs = fmaf(base[c], Wm[c], pBs);
        }
        c4[n] = make_float4(sB, pBs, dB, __int_as_float(chA | (chB << 16)));
    } else if (gid < PREP_ITEMS) {
        const int i = gid - NCROSS;
        const int s = e_src[i];
        const int d = e_dst[i];
        const int slot = atomicAdd(&counts[d], 1);
        if (slot < CAP) bucket[(size_t)d * CAP + slot] = s;
    }
}

// ---------------- GAT aggregation + MLP + sigmoid ----------------------------
// Block = 64 nodes x 4 tick-lanes. The 4 lanes of a quad own the SAME node at
// 4 consecutive tick-groups: their bucket/c4 gather addresses are identical
// (coalescer merges to one L2 request) and their x[ch] float4 reads are 64
// consecutive bytes (one line). Gathers amortized 4x in-flight; no LDS x
// staging, no per-tg barriers.

__device__ __forceinline__ void upd(float& mx, float& den, float& p,
                                    const float e, const float pj) {
    const float dif = e - mx;
    const float ex = __expf(-fabsf(dif));
    const bool g = dif > 0.f;
    const float scale = g ? ex : 1.f;
    const float w = g ? 1.f : ex;
    mx = g ? e : mx;
    den = fmaf(den, scale, w);
    p = fmaf(p, scale, w * pj);
}

__device__ __forceinline__ void edge_proc(const bool valid, const float4 cs,
                                          const float4 a4, const float4 b4,
                                          const float sA1, const float sB1,
                                          const float pA1, const float pB1,
                                          const float* tp, const float* dm,
                                          float* mx, float* den, float* pa) {
    const float a[4] = {a4.x, a4.y, a4.z, a4.w};
    const float b[4] = {b4.x, b4.y, b4.z, b4.w};
#pragma unroll
    for (int k = 0; k < TG; k++) {
        // dm[k] already contains dd[k] + tk*sT (the src tick term folded in)
        float e = cs.x + a[k] * sA1 + b[k] * sB1 + dm[k];
        e = fmaxf(e, 0.2f * e);
        const float pv = cs.y + a[k] * pA1 + b[k] * pB1 + tp[k];
        if (valid) upd(mx[k], den[k], pa[k], e, pv);
    }
}

__global__ __launch_bounds__(256, 4) void k_gat(
        const float* __restrict__ x,
        const float4* __restrict__ c4,
        const int* __restrict__ counts,
        const int* __restrict__ bucket,
        const float* __restrict__ Wg,
        const float* __restrict__ as_,
        const float* __restrict__ ad_,
        const float* __restrict__ Wm,
        const float* __restrict__ bm,
        float* __restrict__ out) {
    const int lid = blockIdx.x;
    const int tgb = lid & 7;            // tick chunk 0..7 (16 ticks each)
    const int nb  = lid >> 3;           // node window 0..NBLKN-1
    const int bbase = nb * BNODE;
    const int tid = threadIdx.x;
    const int wsz = min(BNODE, NCROSS - bbase);

    __shared__ int perm[BNODE];         // packed: local idx | deg<<16
    __shared__ int bins[CAP + 1];
    __shared__ int boff[CAP + 1];
    __shared__ float lres[TGB][BNODE + 2];

    // 9 global projection scalars (uniform -> scalar loads)
    float sA1 = 0, dA1 = 0, pA1 = 0, sB1 = 0, dB1 = 0, pB1 = 0,
          sT = 0, dT = 0, pT = 0;
#pragma unroll
    for (int c = 0; c < 4; c++) {
        const float va = as_[c], vd = ad_[c], vm = Wm[c];
        const float w0 = Wg[c], w5 = Wg[5 * 4 + c], w12 = Wg[12 * 4 + c];
        sA1 = fmaf(w0, va, sA1);  dA1 = fmaf(w0, vd, dA1);  pA1 = fmaf(w0, vm, pA1);
        sB1 = fmaf(w5, va, sB1);  dB1 = fmaf(w5, vd, dB1);  pB1 = fmaf(w5, vm, pB1);
        sT  = fmaf(w12, va, sT);  dT  = fmaf(w12, vd, dT);  pT  = fmaf(w12, vm, pT);
    }

    // ---- block-local descending-degree counting sort (wave-uniform trips) ----
    int deg0 = 0;
    if (tid < wsz) deg0 = min(counts[bbase + tid], CAP);
    if (tid <= CAP) bins[tid] = 0;
    __syncthreads();
    int lp = 0;
    if (tid < wsz) lp = atomicAdd(&bins[deg0], 1);
    __syncthreads();
    if (tid <= CAP) {                   // parallel suffix-sum (desc order)
        int run = 0;
        for (int e = tid + 1; e <= CAP; e++) run += bins[e];
        boff[tid] = run;
    }
    __syncthreads();
    if (tid < wsz) perm[boff[deg0] + lp] = tid | (deg0 << 16);
    __syncthreads();

    const int nq  = tid >> 2;           // node slot 0..63
    const int tgl = tid & 3;            // tick lane 0..3
    const int tg  = tgb * 4 + tgl;      // tick group 0..31

    if (nq < wsz) {
        const int pk = perm[nq];
        const int nloc = pk & 0xffff;
        const int deg = pk >> 16;
        const int n = bbase + nloc;

        const float4 cc = c4[n];        // quad-merged (same addr x4 lanes)
        const int cab = __float_as_int(cc.w);
        const float4 a4 = *(const float4*)(x + (cab & 0xffff) * T_TICKS + tg * TG);
        const float4 b4 = *(const float4*)(x + (cab >> 16) * T_TICKS + tg * TG);
        const float a[4] = {a4.x, a4.y, a4.z, a4.w};
        const float b[4] = {b4.x, b4.y, b4.z, b4.w};

        float dm[TG], tp[TG];
#pragma unroll
        for (int k = 0; k < TG; k++) {
            const float tk = (float)(tg * TG + k);
            // dst d-projection + src tick term folded together
            dm[k] = cc.z + a[k] * dA1 + b[k] * dB1 + tk * dT + tk * sT;
            tp[k] = tk * pT;
        }
        float mx[TG], den[TG], pa[TG];
#pragma unroll
        for (int k = 0; k < TG; k++) { mx[k] = -INFINITY; den[k] = 0.f; pa[k] = 0.f; }

        const int* bkt = bucket + (size_t)n * CAP;
        for (int j = 0; j < deg; j += 4) {
            const int4 bb = *(const int4*)(bkt + j);
            const int m = deg - j;
            // clamp invalid slots to a safe index: loads unconditional (ILP),
            // validity gates only the register-side accumulate.
            const int s0 = bb.x;
            const int s1 = (m > 1) ? bb.y : bb.x;
            const int s2 = (m > 2) ? bb.z : bb.x;
            const int s3 = (m > 3) ? bb.w : bb.x;
            const float4 cs0 = c4[s0];
            const float4 cs1 = c4[s1];
            const float4 cs2 = c4[s2];
            const float4 cs3 = c4[s3];
            const int i0 = __float_as_int(cs0.w);
            const int i1 = __float_as_int(cs1.w);
            const int i2 = __float_as_int(cs2.w);
            const int i3 = __float_as_int(cs3.w);
            const float4 xa0 = *(const float4*)(x + (i0 & 0xffff) * T_TICKS + tg * TG);
            const float4 xb0 = *(const float4*)(x + (i0 >> 16) * T_TICKS + tg * TG);
            const float4 xa1 = *(const float4*)(x + (i1 & 0xffff) * T_TICKS + tg * TG);
            const float4 xb1 = *(const float4*)(x + (i1 >> 16) * T_TICKS + tg * TG);
            const float4 xa2 = *(const float4*)(x + (i2 & 0xffff) * T_TICKS + tg * TG);
            const float4 xb2 = *(const float4*)(x + (i2 >> 16) * T_TICKS + tg * TG);
            const float4 xa3 = *(const float4*)(x + (i3 & 0xffff) * T_TICKS + tg * TG);
            const float4 xb3 = *(const float4*)(x + (i3 >> 16) * T_TICKS + tg * TG);
            edge_proc(true,  cs0, xa0, xb0, sA1, sB1, pA1, pB1, tp, dm, mx, den, pa);
            edge_proc(m > 1, cs1, xa1, xb1, sA1, sB1, pA1, pB1, tp, dm, mx, den, pa);
            edge_proc(m > 2, cs2, xa2, xb2, sA1, sB1, pA1, pB1, tp, dm, mx, den, pa);
            edge_proc(m > 3, cs3, xa3, xb3, sA1, sB1, pA1, pB1, tp, dm, mx, den, pa);
        }

        const float bb2 = bm[0];
#pragma unroll
        for (int k = 0; k < TG; k++) {
            const float logit = pa[k] / (den[k] + 1e-9f) + bb2;
            lres[tgl * 4 + k][nloc] = 1.f / (1.f + __expf(-logit));
        }
    }
    __syncthreads();

    // coalesced un-permuted store: wave w writes rows 4w..4w+3, lane = col
    {
        const int col = tid & 63;
        const int wv  = tid >> 6;
        if (col < wsz) {
#pragma unroll
            for (int rr = 0; rr < 4; rr++) {
                const int row = wv * 4 + rr;
                out[(size_t)(tgb * TGB + row) * NCROSS + bbase + col] =
                    lres[row][col];
            }
        }
    }
}

// ---------------- launch ----------------

extern "C" void kernel_launch(void* const* d_in, const int* in_sizes, int n_in,
                              void* d_out, int out_size, void* d_ws, size_t ws_size,
                              hipStream_t stream) {
    const float* x   = (const float*)d_in[0];
    const int* c0  = (const int*)d_in[1];
    const int* c1  = (const int*)d_in[2];
    const int* c2  = (const int*)d_in[3];
    const int* g01 = (const int*)d_in[4];
    const int* g12 = (const int*)d_in[5];
    const int* g20 = (const int*)d_in[6];
    const float* r01 = (const float*)d_in[7];
    const float* r12 = (const float*)d_in[8];
    const float* r20 = (const float*)d_in[9];
    const int* edges = (const int*)d_in[10];          // [2, E]
    const float* Wg  = (const float*)d_in[11];
    const float* as_ = (const float*)d_in[12];
    const float* ad_ = (const float*)d_in[13];
    const float* bg  = (const float*)d_in[14];
    const float* Wm  = (const float*)d_in[15];
    const float* bm  = (const float*)d_in[16];
    float* out = (float*)d_out;

    const int* e_src = edges;
    const int* e_dst = edges + E_EDGES;

    // workspace layout (~4.5 MB total)
    char* ws = (char*)d_ws;
    size_t off = 0;
    int* counts = (int*)(ws + off); off += NCROSS * sizeof(int);
    off = (off + 255) & ~(size_t)255;
    int* bucket = (int*)(ws + off); off += (size_t)NCROSS * CAP * sizeof(int);  // 3.84 MB
    off = (off + 255) & ~(size_t)255;
    float4* c4 = (float4*)(ws + off); off += (size_t)NCROSS * sizeof(float4);   // 480 KB
    (void)ws_size; (void)n_in; (void)in_sizes; (void)out_size;

    hipMemsetAsync(counts, 0, NCROSS * sizeof(int), stream);

    k_prep<<<(PREP_ITEMS + 255) / 256, 256, 0, stream>>>(
        x, c0, c1, c2, g01, g12, g20, r01, r12, r20, Wg, bg, as_, ad_, Wm,
        e_src, e_dst, counts, bucket, c4);

    k_gat<<<NBLKN * NCHUNK, 256, 0, stream>>>(x, c4, counts, bucket,
                                              Wg, as_, ad_, Wm, bm, out);
}